// Round 8
// baseline (741.184 us; speedup 1.0000x reference)
//
#include <hip/hip_runtime.h>

typedef float f32x2 __attribute__((ext_vector_type(2)));
typedef unsigned int u32;

// bf16-pair helpers: one u32 holds two adjacent-column bf16 values.
// Unpack is exact (bf16 -> f32 is a shift/mask); pack is round-to-nearest-even.
static __device__ __forceinline__ float blo(u32 u) { return __uint_as_float(u << 16); }
static __device__ __forceinline__ float bhi(u32 u) { return __uint_as_float(u & 0xffff0000u); }
static __device__ __forceinline__ u32 bpack(float lo, float hi) {
    u32 ul = __float_as_uint(lo);
    u32 uh = __float_as_uint(hi);
    ul = (ul + 0x7fffu + ((ul >> 16) & 1u)) >> 16;
    uh = (uh + 0x7fffu + ((uh >> 16) & 1u)) & 0xffff0000u;
    return ul | uh;
}
static __device__ __forceinline__ f32x2 bun(u32 u) { return (f32x2){blo(u), bhi(u)}; }

#define NIT 21
#define SMIN 1e-33f

// One 64-thread wave per 128x128 matrix; NO LDS, NO barriers, NO inline asm
// (r5/r6 post-mortem: "v"-constrained pk-asm under >256-VGPR pressure corrupts).
// Lane (lr=lane>>3, lc=lane&7) owns rows lr*16..+15 and cols {g*32+lc*4..+3}.
// E kept as bf16 pairs: u32 E[16][8] = 128 VGPR -> fits 2 waves/SIMD
// (__launch_bounds__(64,2)). All sums/factors f32; cross-lane = __shfl_xor
// only (validated r7). Linear-space Sinkhorn with lazy rcp factors.
__global__ __launch_bounds__(64, 2) void sinkhorn_kernel(const float* __restrict__ in,
                                                         float* __restrict__ out) {
    const int lane = threadIdx.x;
    const int lr = lane >> 3;
    const int lc = lane & 7;
    const size_t base = (size_t)blockIdx.x * (128 * 128);
    const float* __restrict__ src = in  + base + ((size_t)lr << 11) + (lc << 2);
    float*       __restrict__ dst = out + base + ((size_t)lr << 11) + (lc << 2);

    const float S = 36.067376022224085f;  // (1/0.04) * log2(e)

    u32 E[16][8];
    float a[16];
    f32x2 b2[8];

    // ---- init: row max, E = bf16(2^((x-m)*S)), a = rcp(rowsum) ----
#pragma unroll
    for (int r = 0; r < 16; ++r) {
        float4 f0 = *(const float4*)(src + (r << 7));
        float4 f1 = *(const float4*)(src + (r << 7) + 32);
        float4 f2 = *(const float4*)(src + (r << 7) + 64);
        float4 f3 = *(const float4*)(src + (r << 7) + 96);
        float v[16] = {f0.x, f0.y, f0.z, f0.w, f1.x, f1.y, f1.z, f1.w,
                       f2.x, f2.y, f2.z, f2.w, f3.x, f3.y, f3.z, f3.w};
        float m = v[0];
#pragma unroll
        for (int c = 1; c < 16; ++c) m = fmaxf(m, v[c]);
        m = fmaxf(m, __shfl_xor(m, 1));
        m = fmaxf(m, __shfl_xor(m, 2));
        m = fmaxf(m, __shfl_xor(m, 4));
        const float nms = -m * S;
        float s = 0.f;
#pragma unroll
        for (int p = 0; p < 8; ++p) {
            float e0 = __builtin_amdgcn_exp2f(fmaf(v[2 * p],     S, nms));
            float e1 = __builtin_amdgcn_exp2f(fmaf(v[2 * p + 1], S, nms));
            E[r][p] = bpack(e0, e1);
            s += e0 + e1;
        }
        s += __shfl_xor(s, 1);
        s += __shfl_xor(s, 2);
        s += __shfl_xor(s, 4);
        a[r] = __builtin_amdgcn_rcpf(fmaxf(s, SMIN));   // s in [1,128]
    }

#pragma unroll 1
    for (int it = 0; it < NIT; ++it) {
        // ---- col phase: b_c = rcp( sum over 128 rows of E * a ) ----
        f32x2 sc2[8];
#pragma unroll
        for (int p = 0; p < 8; ++p) sc2[p] = (f32x2){0.f, 0.f};
#pragma unroll
        for (int r = 0; r < 16; ++r) {
            const f32x2 ar2 = {a[r], a[r]};
#pragma unroll
            for (int p = 0; p < 8; ++p) sc2[p] += bun(E[r][p]) * ar2;
        }
#pragma unroll
        for (int p = 0; p < 8; ++p) {
            f32x2 v = sc2[p];
            v.x += __shfl_xor(v.x, 8);  v.y += __shfl_xor(v.y, 8);
            v.x += __shfl_xor(v.x, 16); v.y += __shfl_xor(v.y, 16);
            v.x += __shfl_xor(v.x, 32); v.y += __shfl_xor(v.y, 32);
            b2[p].x = __builtin_amdgcn_rcpf(fmaxf(v.x, SMIN));
            b2[p].y = __builtin_amdgcn_rcpf(fmaxf(v.y, SMIN));
        }
        // ---- row phase: a_r = rcp( sum over 128 cols of E * b )  (skip after last col) ----
        if (it < NIT - 1) {
#pragma unroll
            for (int r = 0; r < 16; ++r) {
                f32x2 s2 = {0.f, 0.f};
#pragma unroll
                for (int p = 0; p < 8; ++p) s2 += bun(E[r][p]) * b2[p];
                float s = s2.x + s2.y;
                s += __shfl_xor(s, 1);
                s += __shfl_xor(s, 2);
                s += __shfl_xor(s, 4);
                a[r] = __builtin_amdgcn_rcpf(fmaxf(s, SMIN));
            }
        }
    }

    // ---- epilogue: out = E * a_r * b_c (f32 stores) ----
#pragma unroll
    for (int r = 0; r < 16; ++r) {
        const float ar = a[r];
#pragma unroll
        for (int g = 0; g < 4; ++g) {
            const u32 u0 = E[r][2 * g];
            const u32 u1 = E[r][2 * g + 1];
            float4 o;
            o.x = blo(u0) * ar * b2[2 * g].x;
            o.y = bhi(u0) * ar * b2[2 * g].y;
            o.z = blo(u1) * ar * b2[2 * g + 1].x;
            o.w = bhi(u1) * ar * b2[2 * g + 1].y;
            *(float4*)(dst + (r << 7) + (g << 5)) = o;
        }
    }
}

extern "C" void kernel_launch(void* const* d_in, const int* in_sizes, int n_in,
                              void* d_out, int out_size, void* d_ws, size_t ws_size,
                              hipStream_t stream) {
    (void)n_in; (void)d_ws; (void)ws_size; (void)out_size;
    const float* in  = (const float*)d_in[0];
    float*       out = (float*)d_out;
    const int n_mat = in_sizes[0] / (128 * 128);  // 4096
    sinkhorn_kernel<<<dim3(n_mat), dim3(64), 0, stream>>>(in, out);
}

// Round 9
// 300.150 us; speedup vs baseline: 2.4694x; 2.4694x over previous
//
#include <hip/hip_runtime.h>

#define NIT 21
#define SMIN 1e-33f

// Two 128x128 matrices per 256-thread block (r2 structure + dual-matrix ILP).
// Thread t owns an 8x8 tile of EACH matrix: rows rg*8.., cols cg*8..
// (rg=t>>4, cg=t&15). Linear-space Sinkhorn, kernel E=2^((x-m)*S) fixed in
// registers, lazy rcp factors a_i/b_j. The two matrices are independent
// instruction streams -> fills shfl/LDS/barrier latency that capped r2 at
// VALUBusy 64%. Scalar f32 only, no inline asm (r5/r6 lesson), shfl_xor only.
// ~200 VGPR; __launch_bounds__(256,2) => 256-VGPR cap, no spill (r8 lesson:
// watch FETCH_SIZE for scratch traffic).
__global__ __launch_bounds__(256, 2) void sinkhorn_kernel(const float* __restrict__ in,
                                                          float* __restrict__ out) {
    const int t  = threadIdx.x;
    const int rg = t >> 4;
    const int cg = t & 15;
    const int wv = t >> 6;
    const size_t base = (size_t)blockIdx.x * (2 * 128 * 128);
    const size_t toff = ((size_t)rg << 10) + ((size_t)cg << 3);

    const float S = 36.067376022224085f;  // (1/0.04) * log2(e)

    float E[2][8][8];
    float a[2][8], b[2][8];

    // ---- load + init per matrix: row max, E = 2^((x-m)*S), a = rcp(rowsum) ----
#pragma unroll
    for (int mm = 0; mm < 2; ++mm) {
        const float* __restrict__ src = in + base + (size_t)mm * 16384 + toff;
#pragma unroll
        for (int i = 0; i < 8; ++i) {
            float4 f0 = *(const float4*)(src + (i << 7));
            float4 f1 = *(const float4*)(src + (i << 7) + 4);
            E[mm][i][0] = f0.x; E[mm][i][1] = f0.y; E[mm][i][2] = f0.z; E[mm][i][3] = f0.w;
            E[mm][i][4] = f1.x; E[mm][i][5] = f1.y; E[mm][i][6] = f1.z; E[mm][i][7] = f1.w;
        }
#pragma unroll
        for (int i = 0; i < 8; ++i) {
            float m = E[mm][i][0];
#pragma unroll
            for (int j = 1; j < 8; ++j) m = fmaxf(m, E[mm][i][j]);
            m = fmaxf(m, __shfl_xor(m, 1));
            m = fmaxf(m, __shfl_xor(m, 2));
            m = fmaxf(m, __shfl_xor(m, 4));
            m = fmaxf(m, __shfl_xor(m, 8));
            const float nms = -m * S;
            float s0 = 0.f, s1 = 0.f;
#pragma unroll
            for (int j = 0; j < 8; ++j) {
                float e = __builtin_amdgcn_exp2f(fmaf(E[mm][i][j], S, nms));
                E[mm][i][j] = e;
                if (j & 1) s1 += e; else s0 += e;
            }
            float s = s0 + s1;
            s += __shfl_xor(s, 1);
            s += __shfl_xor(s, 2);
            s += __shfl_xor(s, 4);
            s += __shfl_xor(s, 8);
            a[mm][i] = __builtin_amdgcn_rcpf(fmaxf(s, SMIN));   // s in [1,128]
        }
    }

    // cross-wave col partials: [dbuf][matrix][wave][32 float4-slots], split-quad
    // layout (slots cg and 16+cg) -> 2-way bank aliasing (free).
    __shared__ float4 part[2][2][4][32];
    int pb = 0;

#pragma unroll 1
    for (int it = 0; it < NIT; ++it) {
        // ---- col phase (both matrices): b_j = rcp( sum_i E_ij * a_i ) ----
        float sc[2][8];
#pragma unroll
        for (int mm = 0; mm < 2; ++mm) {
#pragma unroll
            for (int j = 0; j < 8; ++j) sc[mm][j] = 0.f;
#pragma unroll
            for (int i = 0; i < 8; ++i) {
                const float ar = a[mm][i];
#pragma unroll
                for (int j = 0; j < 8; ++j) sc[mm][j] = fmaf(E[mm][i][j], ar, sc[mm][j]);
            }
        }
#pragma unroll
        for (int mm = 0; mm < 2; ++mm) {
#pragma unroll
            for (int j = 0; j < 8; ++j) {   // reduce over the 4 row-groups in this wave
                float s = sc[mm][j];
                s += __shfl_xor(s, 16);
                s += __shfl_xor(s, 32);
                sc[mm][j] = s;
            }
        }
        if ((t & 63) < 16) {
            const int sl = t & 15;
            part[pb][0][wv][sl]      = make_float4(sc[0][0], sc[0][1], sc[0][2], sc[0][3]);
            part[pb][0][wv][16 + sl] = make_float4(sc[0][4], sc[0][5], sc[0][6], sc[0][7]);
            part[pb][1][wv][sl]      = make_float4(sc[1][0], sc[1][1], sc[1][2], sc[1][3]);
            part[pb][1][wv][16 + sl] = make_float4(sc[1][4], sc[1][5], sc[1][6], sc[1][7]);
        }
        __syncthreads();
#pragma unroll
        for (int mm = 0; mm < 2; ++mm) {
            float4 lo = part[pb][mm][0][cg];
            float4 hi = part[pb][mm][0][16 + cg];
#pragma unroll
            for (int w = 1; w < 4; ++w) {
                float4 l2 = part[pb][mm][w][cg];
                float4 h2 = part[pb][mm][w][16 + cg];
                lo.x += l2.x; lo.y += l2.y; lo.z += l2.z; lo.w += l2.w;
                hi.x += h2.x; hi.y += h2.y; hi.z += h2.z; hi.w += h2.w;
            }
            b[mm][0] = __builtin_amdgcn_rcpf(fmaxf(lo.x, SMIN));
            b[mm][1] = __builtin_amdgcn_rcpf(fmaxf(lo.y, SMIN));
            b[mm][2] = __builtin_amdgcn_rcpf(fmaxf(lo.z, SMIN));
            b[mm][3] = __builtin_amdgcn_rcpf(fmaxf(lo.w, SMIN));
            b[mm][4] = __builtin_amdgcn_rcpf(fmaxf(hi.x, SMIN));
            b[mm][5] = __builtin_amdgcn_rcpf(fmaxf(hi.y, SMIN));
            b[mm][6] = __builtin_amdgcn_rcpf(fmaxf(hi.z, SMIN));
            b[mm][7] = __builtin_amdgcn_rcpf(fmaxf(hi.w, SMIN));
        }
        pb ^= 1;

        // ---- row phase (both matrices): a_i = rcp( sum_j E_ij * b_j ) ----
        if (it < NIT - 1) {
#pragma unroll
            for (int mm = 0; mm < 2; ++mm) {
#pragma unroll
                for (int i = 0; i < 8; ++i) {
                    float s0 = 0.f, s1 = 0.f;
#pragma unroll
                    for (int j = 0; j < 8; ++j) {
                        if (j & 1) s1 = fmaf(E[mm][i][j], b[mm][j], s1);
                        else       s0 = fmaf(E[mm][i][j], b[mm][j], s0);
                    }
                    float s = s0 + s1;
                    s += __shfl_xor(s, 1);
                    s += __shfl_xor(s, 2);
                    s += __shfl_xor(s, 4);
                    s += __shfl_xor(s, 8);
                    a[mm][i] = __builtin_amdgcn_rcpf(fmaxf(s, SMIN));
                }
            }
        }
    }

    // ---- epilogue: out = E * a_i * b_j ----
#pragma unroll
    for (int mm = 0; mm < 2; ++mm) {
        float* __restrict__ dst = out + base + (size_t)mm * 16384 + toff;
#pragma unroll
        for (int i = 0; i < 8; ++i) {
            const float ar = a[mm][i];
            float4 o0, o1;
            o0.x = E[mm][i][0] * ar * b[mm][0];
            o0.y = E[mm][i][1] * ar * b[mm][1];
            o0.z = E[mm][i][2] * ar * b[mm][2];
            o0.w = E[mm][i][3] * ar * b[mm][3];
            o1.x = E[mm][i][4] * ar * b[mm][4];
            o1.y = E[mm][i][5] * ar * b[mm][5];
            o1.z = E[mm][i][6] * ar * b[mm][6];
            o1.w = E[mm][i][7] * ar * b[mm][7];
            *(float4*)(dst + (i << 7))     = o0;
            *(float4*)(dst + (i << 7) + 4) = o1;
        }
    }
}

extern "C" void kernel_launch(void* const* d_in, const int* in_sizes, int n_in,
                              void* d_out, int out_size, void* d_ws, size_t ws_size,
                              hipStream_t stream) {
    (void)n_in; (void)d_ws; (void)ws_size; (void)out_size;
    const float* in  = (const float*)d_in[0];
    float*       out = (float*)d_out;
    const int n_mat = in_sizes[0] / (128 * 128);  // 4096
    sinkhorn_kernel<<<dim3(n_mat / 2), dim3(256), 0, stream>>>(in, out);
}

// Round 10
// 167.676 us; speedup vs baseline: 4.4203x; 1.7901x over previous
//
#include <hip/hip_runtime.h>

typedef float f32x2 __attribute__((ext_vector_type(2)));

#define NIT 21
#define SMIN 1e-33f

// DPP quad-perm / row-rotate all-reduce over each 16-lane group (VALU pipe).
// Validated in passing rounds 2/4.
template<int CTRL>
static __device__ __forceinline__ float dppmov(float v) {
    return __int_as_float(__builtin_amdgcn_mov_dpp(__float_as_int(v), CTRL, 0xF, 0xF, true));
}
static __device__ __forceinline__ float sum16(float v) {
    v += dppmov<0xB1>(v);    // xor1
    v += dppmov<0x4E>(v);    // xor2
    v += dppmov<0x124>(v);   // row_ror:4
    v += dppmov<0x128>(v);   // row_ror:8
    return v;
}
static __device__ __forceinline__ float max16(float v) {
    v = fmaxf(v, dppmov<0xB1>(v));
    v = fmaxf(v, dppmov<0x4E>(v));
    v = fmaxf(v, dppmov<0x124>(v));
    v = fmaxf(v, dppmov<0x128>(v));
    return v;
}

#if __has_builtin(__builtin_amdgcn_permlane16_swap) && __has_builtin(__builtin_amdgcn_permlane32_swap)
#define HAVE_PLSWAP 1
// v_permlane16_swap_b32: odd 16-rows of A <-> even 16-rows of B (VALU).
// plsum16(A,B) returns per 16-row q: [A.r0+A.r1, B.r0+B.r1, A.r2+A.r3, B.r2+B.r3]
static __device__ __forceinline__ float plsum16(float A, float B) {
    auto r = __builtin_amdgcn_permlane16_swap(__float_as_uint(A), __float_as_uint(B), false, false);
    return __uint_as_float(r[0]) + __uint_as_float(r[1]);
}
// v_permlane32_swap_b32: hi half of A <-> lo half of B (VALU).
// plsum32(X,Y) returns rows [X.r0+X.r2, X.r1+X.r3, Y.r0+Y.r2, Y.r1+Y.r3]
static __device__ __forceinline__ float plsum32(float X, float Y) {
    auto r = __builtin_amdgcn_permlane32_swap(__float_as_uint(X), __float_as_uint(Y), false, false);
    return __uint_as_float(r[0]) + __uint_as_float(r[1]);
}
#else
#define HAVE_PLSWAP 0
#endif

// One 256-thread block per 128x128 matrix (r2 regime: 8x8 tile/thread,
// ~110 VGPR, no allocator pathology). Linear-space Sinkhorn: E = 2^((x-m)*S)
// fixed in registers as f32x2[8][4]; lazy rcp factors a_i/b_j.
// Round-10 change: col-phase cross-lane reduce via permlane16/32_swap pair
// trick (VALU) instead of 16 shfl (DS) -> DS ops/iter 26 -> 10, no divergent
// store. LDS layout identical to r2 (contiguous 1KB/wave, 2-way banks).
__global__ __launch_bounds__(256, 3) void sinkhorn_kernel(const float* __restrict__ in,
                                                          float* __restrict__ out) {
    const int t  = threadIdx.x;
    const int rg = t >> 4;      // row-group 0..15 (rows rg*8..+7)
    const int cg = t & 15;      // col-group (cols cg*8..+7); == lane&15
    const int wv = t >> 6;      // wave 0..3
    const int q  = rg & 3;      // 16-lane row index within wave
    const size_t base = (size_t)blockIdx.x * (128 * 128);
    const float* __restrict__ src = in  + base + ((size_t)rg << 10) + ((size_t)cg << 3);
    float*       __restrict__ dst = out + base + ((size_t)rg << 10) + ((size_t)cg << 3);

    const float S = 36.067376022224085f;  // (1/0.04) * log2(e)

    f32x2 E[8][4];
    float a[8];
    f32x2 b2[4];

    // ---- init: row max, E = 2^((x-m)*S), a = rcp(rowsum)  (r2-proven) ----
#pragma unroll
    for (int i = 0; i < 8; ++i) {
        float4 f0 = *(const float4*)(src + (i << 7));
        float4 f1 = *(const float4*)(src + (i << 7) + 4);
        E[i][0] = (f32x2){f0.x, f0.y};
        E[i][1] = (f32x2){f0.z, f0.w};
        E[i][2] = (f32x2){f1.x, f1.y};
        E[i][3] = (f32x2){f1.z, f1.w};
        f32x2 m2 = E[i][0];
#pragma unroll
        for (int j = 1; j < 4; ++j) {
            m2.x = fmaxf(m2.x, E[i][j].x);
            m2.y = fmaxf(m2.y, E[i][j].y);
        }
        float m = max16(fmaxf(m2.x, m2.y));
        const float nms = -m * S;
        float s = 0.f;
#pragma unroll
        for (int j = 0; j < 4; ++j) {
            f32x2 e;
            e.x = __builtin_amdgcn_exp2f(fmaf(E[i][j].x, S, nms));
            e.y = __builtin_amdgcn_exp2f(fmaf(E[i][j].y, S, nms));
            E[i][j] = e;
            s += e.x + e.y;
        }
        s = sum16(s);
        a[i] = __builtin_amdgcn_rcpf(fmaxf(s, SMIN));   // rowsum in [1,128]
    }

    // col partials: [dbuf][wave][128 floats]; float idx s*4+q (cols 0..3 of
    // group s) and 64+s*4+q (cols 4..7) == r2's split-quad float4 layout.
    __shared__ float part[2][4][128];
    int pb = 0;

#pragma unroll 1
    for (int it = 0; it < NIT; ++it) {
        // ---- col phase: b_j = rcp( sum_i E_ij * a_i ) ----
        f32x2 sc[4];
#pragma unroll
        for (int j = 0; j < 4; ++j) sc[j] = (f32x2){0.f, 0.f};
#pragma unroll
        for (int i = 0; i < 8; ++i) {
            const float ai = a[i];
#pragma unroll
            for (int j = 0; j < 4; ++j) {
                sc[j].x = fmaf(E[i][j].x, ai, sc[j].x);
                sc[j].y = fmaf(E[i][j].y, ai, sc[j].y);
            }
        }
#if HAVE_PLSWAP
        // in-wave reduce over the 4 row-groups, all VALU:
        // stage1 pairs (col0,col1),(col2,col3),(col4,col5),(col6,col7)
        float s01 = plsum16(sc[0].x, sc[0].y);
        float s23 = plsum16(sc[1].x, sc[1].y);
        float s45 = plsum16(sc[2].x, sc[2].y);
        float s67 = plsum16(sc[3].x, sc[3].y);
        // stage2: X1 rows q=[col0,col1,col2,col3], X2 rows q=[col4..col7]
        float X1 = plsum32(s01, s23);
        float X2 = plsum32(s45, s67);
        // every lane stores one scalar; layout == r2 readback layout
        part[pb][wv][(cg << 2) + q]      = X1;
        part[pb][wv][64 + (cg << 2) + q] = X2;
#else
#pragma unroll
        for (int j = 0; j < 4; ++j) {
            sc[j].x += __shfl_xor(sc[j].x, 16); sc[j].y += __shfl_xor(sc[j].y, 16);
            sc[j].x += __shfl_xor(sc[j].x, 32); sc[j].y += __shfl_xor(sc[j].y, 32);
        }
        if ((t & 63) < 16) {
            float4* p4 = (float4*)part[pb][wv];
            p4[cg]      = make_float4(sc[0].x, sc[0].y, sc[1].x, sc[1].y);
            p4[16 + cg] = make_float4(sc[2].x, sc[2].y, sc[3].x, sc[3].y);
        }
#endif
        __syncthreads();
        {
            const float4* p0 = (const float4*)part[pb][0];
            const float4* p1 = (const float4*)part[pb][1];
            const float4* p2 = (const float4*)part[pb][2];
            const float4* p3 = (const float4*)part[pb][3];
            float4 lo = p0[cg];
            float4 hi = p0[16 + cg];
            float4 l1 = p1[cg], h1 = p1[16 + cg];
            float4 l2 = p2[cg], h2 = p2[16 + cg];
            float4 l3 = p3[cg], h3 = p3[16 + cg];
            lo.x += l1.x + l2.x + l3.x; lo.y += l1.y + l2.y + l3.y;
            lo.z += l1.z + l2.z + l3.z; lo.w += l1.w + l2.w + l3.w;
            hi.x += h1.x + h2.x + h3.x; hi.y += h1.y + h2.y + h3.y;
            hi.z += h1.z + h2.z + h3.z; hi.w += h1.w + h2.w + h3.w;
            b2[0].x = __builtin_amdgcn_rcpf(fmaxf(lo.x, SMIN));
            b2[0].y = __builtin_amdgcn_rcpf(fmaxf(lo.y, SMIN));
            b2[1].x = __builtin_amdgcn_rcpf(fmaxf(lo.z, SMIN));
            b2[1].y = __builtin_amdgcn_rcpf(fmaxf(lo.w, SMIN));
            b2[2].x = __builtin_amdgcn_rcpf(fmaxf(hi.x, SMIN));
            b2[2].y = __builtin_amdgcn_rcpf(fmaxf(hi.y, SMIN));
            b2[3].x = __builtin_amdgcn_rcpf(fmaxf(hi.z, SMIN));
            b2[3].y = __builtin_amdgcn_rcpf(fmaxf(hi.w, SMIN));
        }
        pb ^= 1;

        // ---- row phase: a_i = rcp( sum_j E_ij * b_j )  (skip after last col) ----
        if (it < NIT - 1) {
#pragma unroll
            for (int i = 0; i < 8; ++i) {
                f32x2 s2 = E[i][0] * b2[0];
                s2 += E[i][1] * b2[1];
                s2 += E[i][2] * b2[2];
                s2 += E[i][3] * b2[3];
                float s = sum16(s2.x + s2.y);
                a[i] = __builtin_amdgcn_rcpf(fmaxf(s, SMIN));
            }
        }
    }

    // ---- epilogue: out = E * a_i * b_j ----
#pragma unroll
    for (int i = 0; i < 8; ++i) {
        const float ai = a[i];
        f32x2 p0 = E[i][0] * b2[0];
        f32x2 p1 = E[i][1] * b2[1];
        f32x2 p2 = E[i][2] * b2[2];
        f32x2 p3 = E[i][3] * b2[3];
        float4 o0 = make_float4(p0.x * ai, p0.y * ai, p1.x * ai, p1.y * ai);
        float4 o1 = make_float4(p2.x * ai, p2.y * ai, p3.x * ai, p3.y * ai);
        *(float4*)(dst + (i << 7))     = o0;
        *(float4*)(dst + (i << 7) + 4) = o1;
    }
}

extern "C" void kernel_launch(void* const* d_in, const int* in_sizes, int n_in,
                              void* d_out, int out_size, void* d_ws, size_t ws_size,
                              hipStream_t stream) {
    (void)n_in; (void)d_ws; (void)ws_size; (void)out_size;
    const float* in  = (const float*)d_in[0];
    float*       out = (float*)d_out;
    const int n_mat = in_sizes[0] / (128 * 128);  // 4096
    sinkhorn_kernel<<<dim3(n_mat), dim3(256), 0, stream>>>(in, out);
}